// Round 5
// baseline (164.289 us; speedup 1.0000x reference)
//
#include <hip/hip_runtime.h>
#include <hip/hip_bf16.h>
#include <hip/hip_fp16.h>

// Problem constants (match reference)
#define CUTOFF_C    12.0f
#define CUTOFF_SR_C 2.0f
#define CUTOFF_SQ_C 144.0f
#define KEHALF_C    7.199822675975274f

#define BLK1   1024

// Old-path duo config: 2 blocks/CU. 17408*4 + 1025*8 = 77832 B <= 80 KB.
#define CH_DUO   17408
#define LUT_DUO  1024
// Old-path solo config: 1 block/CU.
#define CH_SOLO  33792
#define LUT_SOLO 2048

// vw-scatter: no LUT in LDS -> CH*4 = 80000 B <= 80 KB, nch=5 for 100K atoms.
#define CH_REC   20000

// Pass-A j-chunk: qd slice of AJ_CH atoms staged in LDS (AJ_CH*4 = 133344 B
// <= 160 KB, 1 block/CU, BLK=1024). AJ_CH % 4 == 0 for uint4 staging.
#define AJ_CH  33336

__device__ __forceinline__ float edge_energy(float d, float qi, float qj,
                                             float di, float dj) {
    float inv_d   = __frcp_rn(d);
    float dsh     = __fsqrt_rn(fmaf(d, d, 1.0f));
    float inv_dsh = __frcp_rn(dsh);
    float x  = d * (1.0f / CUTOFF_SR_C);
    float x3 = x * x * x;
    float sw = fmaf(x3, fmaf(x, fmaf(x, -6.0f, 15.0f), -10.0f), 1.0f);
    float sw_off = (d < CUTOFF_SR_C) ? sw : 0.0f;
    float Eoq = inv_d   + fmaf(d,   (1.0f / CUTOFF_SQ_C), -(2.0f / CUTOFF_C));
    float Esq = inv_dsh + fmaf(dsh, (1.0f / CUTOFF_SQ_C), -(2.0f / CUTOFF_C));
    float Eq  = (KEHALF_C * qi * qj) * fmaf(sw_off, Esq - Eoq, Eoq);
    float Eod = inv_d * inv_d * inv_d;
    float Esd = inv_dsh * inv_dsh * inv_dsh;
    float Ed  = (KEHALF_C * di * dj) * fmaf(sw_off, Esd - Eod, Eod);
    return Eq + Ed;
}

// Exact radial factors (KEHALF folded): v = qj*F, w = dj*G.  (old path / LUT init)
__device__ __forceinline__ float2 fg_exact(float d) {
    float inv_d   = 1.0f / d;
    float dsh     = sqrtf(fmaf(d, d, 1.0f));
    float inv_dsh = 1.0f / dsh;
    float x  = d * (1.0f / CUTOFF_SR_C);
    float x3 = x * x * x;
    float sw = fmaf(x3, fmaf(x, fmaf(x, -6.0f, 15.0f), -10.0f), 1.0f);
    float sw_off = (d < CUTOFF_SR_C) ? sw : 0.0f;
    float Foq = inv_d   + fmaf(d,   (1.0f / CUTOFF_SQ_C), -(2.0f / CUTOFF_C));
    float Fsq = inv_dsh + fmaf(dsh, (1.0f / CUTOFF_SQ_C), -(2.0f / CUTOFF_C));
    float F   = fmaf(sw_off, Fsq - Foq, Foq);
    float God = inv_d * inv_d * inv_d;
    float Gsd = inv_dsh * inv_dsh * inv_dsh;
    float G   = fmaf(sw_off, Gsd - God, God);
    return make_float2(KEHALF_C * F, KEHALF_C * G);
}

__device__ __forceinline__ __half2 vw_make_exact(float d, __half2 hqdj) {
    float2 qdj = __half22float2(hqdj);
    float2 fg  = fg_exact(d);
    return __floats2half2_rn(qdj.x * fg.x, qdj.y * fg.y);
}

__device__ __forceinline__ unsigned h2bits(__half2 h) {
    union { __half2 h; unsigned u; } c; c.h = h; return c.u;
}
__device__ __forceinline__ __half2 bits2h(unsigned u) {
    union { unsigned u; __half2 h; } c; c.u = u; return c.h;
}
// half2 atomic add (LDS): HW atomicAdd(__half2*) (ds_pk_add_f16) if available.
template <typename T>
__device__ __forceinline__ auto atom_add_h2(T* p, T v, int)
    -> decltype(atomicAdd(p, v), void()) {
    atomicAdd(p, v);
}
template <typename T>
__device__ __forceinline__ void atom_add_h2(T* p, T v, long) {
    unsigned* u = (unsigned*)p;
    unsigned old = *u, assumed;
    do {
        assumed = old;
        __half2 sum = __hadd2(bits2h(assumed), v);
        old = atomicCAS(u, assumed, h2bits(sum));
    } while (old != assumed);
}

// Fast-exact per-edge radial factors via HW rcp/rsq (errors << fp16 rounding).
// Returns half2{qj*F, dipj*G} bit-pattern. Validity (d<=cutoff) handled by caller.
__device__ __forceinline__ unsigned vw_bits(float d, unsigned hqbits) {
    float inv_d   = __builtin_amdgcn_rcpf(d);
    float dsh2    = fmaf(d, d, 1.0f);
    float inv_dsh = __builtin_amdgcn_rsqf(dsh2);   // 1/sqrt(d^2+1)
    float dsh     = dsh2 * inv_dsh;                // sqrt(d^2+1)
    float x  = d * (1.0f / CUTOFF_SR_C);
    float x3 = x * x * x;
    float sw = fmaf(x3, fmaf(x, fmaf(x, -6.0f, 15.0f), -10.0f), 1.0f);
    float sw_off = (d < CUTOFF_SR_C) ? sw : 0.0f;
    float Foq = inv_d   + fmaf(d,   (1.0f / CUTOFF_SQ_C), -(2.0f / CUTOFF_C));
    float Fsq = inv_dsh + fmaf(dsh, (1.0f / CUTOFF_SQ_C), -(2.0f / CUTOFF_C));
    float F   = fmaf(sw_off, Fsq - Foq, Foq);
    float God = inv_d * inv_d * inv_d;
    float Gsd = inv_dsh * inv_dsh * inv_dsh;
    float G   = fmaf(sw_off, Gsd - God, God);
    float2 q2 = __half22float2(bits2h(hqbits));
    __half2 vw = __floats2half2_rn((KEHALF_C * q2.x) * F, (KEHALF_C * q2.y) * G);
    return h2bits(vw);
}

// Pack {q, dip} -> half2 (4 B / atom), j-side gather table.
__global__ __launch_bounds__(256) void pc_pack_qd_h(
    const float* __restrict__ q,
    const float* __restrict__ dip,
    __half2*     __restrict__ qd,
    int n_atoms)
{
    int a = blockIdx.x * 256 + threadIdx.x;
    if (a < n_atoms) qd[a] = __floats2half2_rn(q[a], dip[a]);
}

// ---------------- PASS A: per-edge vw precompute, LDS j-gather --------------
// R4 showed register batching is null: the limiter is gather LINE traffic —
// each random 4B qd[j] gather misses L1 (table 400KB) and pulls a 64-128B L2
// line. Fix: stage qd into LDS in njc chunks of AJ_CH atoms; each thread keeps
// its 12 edges (j,d) in registers across the chunk loop and select-accumulates
// qh[k] from LDS. fg math runs once per edge after the loop; 3 coalesced
// uint4 stores. Out-of-cutoff edges -> vw = 0 (exact).
__global__ __launch_bounds__(BLK1) void pc_edge_jlds(
    const float*   __restrict__ dist,
    const int*     __restrict__ idx_j,
    const __half2* __restrict__ qd,
    uint4*         __restrict__ vwo,     // [n4] groups of 4 edges
    unsigned*      __restrict__ vws,     // scalar view (tail records)
    int n_edges, int n4, int third, int n_atoms, int njc)
{
    extern __shared__ unsigned lds_qd[];             // AJ_CH entries
    const int tid = (int)threadIdx.x;
    const int t   = blockIdx.x * BLK1 + tid;
    const int4*   j4p = (const int4*)idx_j;
    const float4* d4p = (const float4*)dist;
    const unsigned* qdu = (const unsigned*)qd;

    const bool active = t < third;
    int  ga = 0, gb = 0, gc = 0;
    bool vb = false, vc = false;
    int4   ja = make_int4(0, 0, 0, 0), jb = ja, jc = ja;
    float4 da = make_float4(0.f, 0.f, 0.f, 0.f), db = da, dc = da;

    if (active) {
        ga = t;
        gb = t + third;
        gc = t + 2 * third;
        vb = gb < n4;
        vc = gc < n4;
        const int gbs = vb ? gb : ga;    // safe addr, cndmask not branch
        const int gcs = vc ? gc : ga;
        ja = j4p[ga];  jb = j4p[gbs];  jc = j4p[gcs];
        da = d4p[ga];  db = d4p[gbs];  dc = d4p[gcs];
    }

    // scalar tail (n_edges % 4): first threads of block 0 carry one extra edge
    const int tl = n_edges & 3;
    const bool tact = (blockIdx.x == 0) && (tid < tl);
    int   jt = 0; float dt = 0.f;
    if (tact) {
        int e = (n4 << 2) + tid;
        jt = idx_j[e];
        dt = dist[e];
    }

    unsigned j12[12] = {
        (unsigned)ja.x, (unsigned)ja.y, (unsigned)ja.z, (unsigned)ja.w,
        (unsigned)jb.x, (unsigned)jb.y, (unsigned)jb.z, (unsigned)jb.w,
        (unsigned)jc.x, (unsigned)jc.y, (unsigned)jc.z, (unsigned)jc.w };
    unsigned qh[12] = { 0u,0u,0u,0u, 0u,0u,0u,0u, 0u,0u,0u,0u };
    unsigned qt = 0u;

    for (int c = 0; c < njc; ++c) {
        const unsigned base = (unsigned)c * (unsigned)AJ_CH;
        const int lim  = min(AJ_CH, n_atoms - (int)base);
        const int lim4 = lim >> 2;

        __syncthreads();
        {   // cooperative stage: coalesced uint4 reads (qd 256B-aligned, AJ_CH%4==0)
            const uint4* src4 = (const uint4*)(qdu + base);
            uint4* dst4 = (uint4*)lds_qd;
            for (int i = tid; i < lim4; i += BLK1) dst4[i] = src4[i];
            for (int i = (lim4 << 2) + tid; i < lim; i += BLK1)
                lds_qd[i] = qdu[base + i];
        }
        __syncthreads();

        if (active) {
            #pragma unroll
            for (int k = 0; k < 12; ++k) {
                unsigned lj = j12[k] - base;
                if (lj < (unsigned)lim) qh[k] = lds_qd[lj];
            }
        }
        if (tact) {
            unsigned lj = (unsigned)jt - base;
            if (lj < (unsigned)lim) qt = lds_qd[lj];
        }
    }

    if (active) {
        unsigned w0  = vw_bits(da.x, qh[0]);
        unsigned w1  = vw_bits(da.y, qh[1]);
        unsigned w2  = vw_bits(da.z, qh[2]);
        unsigned w3  = vw_bits(da.w, qh[3]);
        unsigned w4  = vw_bits(db.x, qh[4]);
        unsigned w5  = vw_bits(db.y, qh[5]);
        unsigned w6  = vw_bits(db.z, qh[6]);
        unsigned w7  = vw_bits(db.w, qh[7]);
        unsigned w8  = vw_bits(dc.x, qh[8]);
        unsigned w9  = vw_bits(dc.y, qh[9]);
        unsigned w10 = vw_bits(dc.z, qh[10]);
        unsigned w11 = vw_bits(dc.w, qh[11]);

        w0  = (da.x <= CUTOFF_C) ? w0  : 0u;
        w1  = (da.y <= CUTOFF_C) ? w1  : 0u;
        w2  = (da.z <= CUTOFF_C) ? w2  : 0u;
        w3  = (da.w <= CUTOFF_C) ? w3  : 0u;
        w4  = (db.x <= CUTOFF_C) ? w4  : 0u;
        w5  = (db.y <= CUTOFF_C) ? w5  : 0u;
        w6  = (db.z <= CUTOFF_C) ? w6  : 0u;
        w7  = (db.w <= CUTOFF_C) ? w7  : 0u;
        w8  = (dc.x <= CUTOFF_C) ? w8  : 0u;
        w9  = (dc.y <= CUTOFF_C) ? w9  : 0u;
        w10 = (dc.z <= CUTOFF_C) ? w10 : 0u;
        w11 = (dc.w <= CUTOFF_C) ? w11 : 0u;

        vwo[ga] = make_uint4(w0, w1, w2, w3);
        if (vb) vwo[gb] = make_uint4(w4, w5, w6, w7);
        if (vc) vwo[gc] = make_uint4(w8, w9, w10, w11);
    }

    if (tact) {
        int e = (n4 << 2) + tid;
        unsigned w = vw_bits(dt, qt);
        vws[e] = (dt <= CUTOFF_C) ? w : 0u;
    }
}

// ---------------- PASS B: vw scatter (8-edge unrolled) ----------------
// Chunked-LDS scatter over precomputed vw: per edge just
// {lc = idx_i[e] - base; if (lc < CH) ds_pk_add_f16}. No gathers, no fg math.
// Block b: s = b % S (edge slice), c = b / S (atom chunk). S % 8 == 0 keeps
// same-slice blocks on one XCD so the nch chunk re-reads hit L2.
template <int CH, int BLK>
__global__ __launch_bounds__(BLK) void pc_scatter_vw(
    const int*      __restrict__ idx_i,
    const unsigned* __restrict__ vw,
    __half2*        __restrict__ partial,   // [S][n_atoms] half2 {sumv,sumw}
    int n_edges, int n4, int S, int gps, int n_atoms)
{
    extern __shared__ char smem[];
    __half2* acc2 = (__half2*)smem;                                  // CH

    const int s = blockIdx.x % S;
    const int c = blockIdx.x / S;
    const unsigned base = (unsigned)(c * CH);
    const int lim = min(CH, n_atoms - (int)base);

    const __half2 hzero = __floats2half2_rn(0.0f, 0.0f);
    for (int i = threadIdx.x; i < CH; i += BLK) acc2[i] = hzero;
    __syncthreads();

    const int4*  i4p = (const int4*)idx_i;
    const uint4* v4p = (const uint4*)vw;
    const int g0 = s * gps;
    const int g1 = min(g0 + gps, n4);
    for (int g = g0 + (int)threadIdx.x; g < g1; g += 2 * BLK) {
        const int  gB   = g + BLK;
        const bool hasB = gB < g1;
        const int  gBs  = hasB ? gB : g;

        int4  iA = i4p[g];
        int4  iB = i4p[gBs];
        uint4 vA = v4p[g];
        uint4 vB = v4p[gBs];

        unsigned a0 = (unsigned)iA.x - base;
        unsigned a1 = (unsigned)iA.y - base;
        unsigned a2 = (unsigned)iA.z - base;
        unsigned a3 = (unsigned)iA.w - base;
        if (a0 < (unsigned)CH) atom_add_h2(&acc2[a0], bits2h(vA.x), 0);
        if (a1 < (unsigned)CH) atom_add_h2(&acc2[a1], bits2h(vA.y), 0);
        if (a2 < (unsigned)CH) atom_add_h2(&acc2[a2], bits2h(vA.z), 0);
        if (a3 < (unsigned)CH) atom_add_h2(&acc2[a3], bits2h(vA.w), 0);
        if (hasB) {
            unsigned b0 = (unsigned)iB.x - base;
            unsigned b1 = (unsigned)iB.y - base;
            unsigned b2 = (unsigned)iB.z - base;
            unsigned b3 = (unsigned)iB.w - base;
            if (b0 < (unsigned)CH) atom_add_h2(&acc2[b0], bits2h(vB.x), 0);
            if (b1 < (unsigned)CH) atom_add_h2(&acc2[b1], bits2h(vB.y), 0);
            if (b2 < (unsigned)CH) atom_add_h2(&acc2[b2], bits2h(vB.z), 0);
            if (b3 < (unsigned)CH) atom_add_h2(&acc2[b3], bits2h(vB.w), 0);
        }
    }

    if (s == S - 1) {  // scalar tail (n_edges % 4)
        for (int e = (n4 << 2) + (int)threadIdx.x; e < n_edges; e += BLK) {
            unsigned lc = (unsigned)idx_i[e] - base;
            if (lc < (unsigned)CH) atom_add_h2(&acc2[lc], bits2h(vw[e]), 0);
        }
    }

    __syncthreads();
    __half2* row = partial + (size_t)s * n_atoms + (int)base;
    for (int i = threadIdx.x; i < lim; i += BLK) row[i] = acc2[i];
}

// ---------------- OLD PATH (fallback): fused compute+scatter with LDS LUT ----
template <int CH, int LUTN, int BLK>
__global__ __launch_bounds__(BLK) void pc_scatter_lut(
    const float*   __restrict__ dist,
    const int*     __restrict__ idx_i,
    const int*     __restrict__ idx_j,
    const __half2* __restrict__ qd,
    __half2*       __restrict__ partial,   // [S][n_atoms] half2 {sumv,sumw}
    int n_edges, int n4, int S, int gps, int n_atoms, int nch)
{
    extern __shared__ char smem[];
    __half2* acc2 = (__half2*)smem;                                  // CH
    float2*  lut  = (float2*)(smem + (size_t)CH * sizeof(__half2));  // LUTN+1

    const int s    = blockIdx.x % S;
    const int c    = blockIdx.x / S;
    const int base = c * CH;
    const int lim  = min(CH, n_atoms - base);

    const __half2 hzero = __floats2half2_rn(0.0f, 0.0f);
    for (int i = threadIdx.x; i < CH; i += BLK) acc2[i] = hzero;

    const float hstep = CUTOFF_C / (float)LUTN;
    for (int k = threadIdx.x; k <= LUTN; k += BLK) {
        float d = fmaxf((float)k * hstep, 0.25f * hstep);
        lut[k] = fg_exact(d);
    }
    __syncthreads();

    const int g0 = s * gps;
    const int g1 = min(g0 + gps, n4);
    const int4*   idxi4 = (const int4*)idx_i;
    const int4*   idxj4 = (const int4*)idx_j;
    const float4* dist4 = (const float4*)dist;
    const float   dscale = (float)LUTN / CUTOFF_C;

    for (int g = g0 + (int)threadIdx.x; g < g1; g += BLK) {
        int4   i4 = idxi4[g];
        int4   j4 = idxj4[g];
        float4 d4 = dist4[g];

        int      ii[4] = { i4.x, i4.y, i4.z, i4.w };
        int      jj[4] = { j4.x, j4.y, j4.z, j4.w };
        float    dd[4] = { d4.x, d4.y, d4.z, d4.w };
        unsigned lc[4];
        bool     vl[4];
        __half2  qh[4];

        #pragma unroll
        for (int k = 0; k < 4; ++k) {
            lc[k] = (unsigned)(ii[k] - base);
            vl[k] = (lc[k] < (unsigned)CH) && (dd[k] <= CUTOFF_C);
        }
        #pragma unroll
        for (int k = 0; k < 4; ++k)
            qh[k] = vl[k] ? qd[jj[k]] : hzero;

        #pragma unroll
        for (int k = 0; k < 4; ++k) {
            if (vl[k]) {
                float t  = dd[k] * dscale;
                int   kk = min((int)t, LUTN - 1);
                float fr = t - (float)kk;
                float2 l0 = lut[kk];
                float2 l1 = lut[kk + 1];
                float F = fmaf(fr, l1.x - l0.x, l0.x);
                float G = fmaf(fr, l1.y - l0.y, l0.y);
                float2 qdj = __half22float2(qh[k]);
                __half2 vw = __floats2half2_rn(qdj.x * F, qdj.y * G);
                atom_add_h2(&acc2[lc[k]], vw, 0);
            }
        }
    }

    if (s == S - 1) {  // scalar tail (n_edges % 4)
        for (int e = (n4 << 2) + (int)threadIdx.x; e < n_edges; e += BLK) {
            int i = idx_i[e];
            float d = dist[e];
            unsigned local = (unsigned)(i - base);
            if (local < (unsigned)CH && d <= CUTOFF_C) {
                __half2 vw = vw_make_exact(d, qd[idx_j[e]]);
                atom_add_h2(&acc2[local], vw, 0);
            }
        }
    }

    __syncthreads();
    __half2* row = partial + (size_t)s * n_atoms + base;
    for (int i = threadIdx.x; i < lim; i += BLK) row[i] = acc2[i];
}

// out[a] = q[a]*sum_s(v) + dip[a]*sum_s(w) — exact fp32 recombination.
// Requires S % 4 == 0.
__global__ __launch_bounds__(256) void pc_reduce_vw(
    const __half2* __restrict__ partial,   // [S][n_atoms]
    const float*   __restrict__ q,
    const float*   __restrict__ dip,
    float*         __restrict__ out,
    int n_atoms, int S)
{
    __shared__ float2 sh[256];
    int a0   = blockIdx.x * 64;
    int lane = threadIdx.x & 63;
    int w    = threadIdx.x >> 6;
    int a    = a0 + lane;

    float sv = 0.0f, sw = 0.0f;
    if (a < n_atoms) {
        int per = S >> 2;                  // S % 4 == 0
        const __half2* p = partial + a;
        int s = w * per, send = s + per;
        for (; s < send; ++s) {
            float2 t = __half22float2(p[(size_t)s * n_atoms]);
            sv += t.x; sw += t.y;
        }
    }
    sh[threadIdx.x] = make_float2(sv, sw);
    __syncthreads();
    if (w == 0 && a < n_atoms) {
        float2 t0 = sh[lane],       t1 = sh[64 + lane];
        float2 t2 = sh[128 + lane], t3 = sh[192 + lane];
        float fv = (t0.x + t1.x) + (t2.x + t3.x);
        float fw = (t0.y + t1.y) + (t2.y + t3.y);
        out[a] = fmaf(q[a], fv, dip[a] * fw);
    }
}

// Full-precision global-atomic fallback (probe failure / tiny ws).
__global__ __launch_bounds__(256) void pc_dipole_edges_atomic(
    const float* __restrict__ q,
    const float* __restrict__ dip,
    const float* __restrict__ dist,
    const int*   __restrict__ idx_i,
    const int*   __restrict__ idx_j,
    float*       __restrict__ out,
    int n_edges)
{
    int t = blockIdx.x * blockDim.x + threadIdx.x;
    const int stride = gridDim.x * blockDim.x;
    for (int e = t; e < n_edges; e += stride) {
        float d = dist[e];
        if (d > CUTOFF_C) continue;
        int i = idx_i[e], j = idx_j[e];
        atomicAdd(&out[i], edge_energy(d, q[i], q[j], dip[i], dip[j]));
    }
}

static int probe_blocks(const void* f, int blk, size_t lds) {
    hipError_t e1 = hipFuncSetAttribute(
        f, hipFuncAttributeMaxDynamicSharedMemorySize, (int)lds);
    int nb = 0;
    hipError_t e2 = hipOccupancyMaxActiveBlocksPerMultiprocessor(&nb, f, blk, lds);
    if (e1 != hipSuccess || e2 != hipSuccess) return 0;
    return nb;
}

extern "C" void kernel_launch(void* const* d_in, const int* in_sizes, int n_in,
                              void* d_out, int out_size, void* d_ws, size_t ws_size,
                              hipStream_t stream) {
    const float* q     = (const float*)d_in[0];
    const float* dip   = (const float*)d_in[1];
    const float* dist  = (const float*)d_in[2];
    const int*   idx_i = (const int*)d_in[3];
    const int*   idx_j = (const int*)d_in[4];
    float*       out   = (float*)d_out;

    int n_edges = in_sizes[2];
    int n_atoms = out_size;
    int n4      = n_edges >> 2;

    // ---------- vw precompute (LDS j-gather) + vw scatter ----------
    size_t qd_b     = ((size_t)n_atoms * sizeof(__half2) + 255) & ~(size_t)255;
    size_t vw_b     = (((size_t)n_edges * 4) + 255) & ~(size_t)255;
    size_t lds_rec  = (size_t)CH_REC * sizeof(__half2);              // 80000 B
    size_t lds_edge = (size_t)AJ_CH * 4;                             // 133344 B

    int nb_rec  = probe_blocks((const void*)&pc_scatter_vw<CH_REC, BLK1>,
                               BLK1, lds_rec);
    int nb_edge = probe_blocks((const void*)&pc_edge_jlds, BLK1, lds_edge);

    int S_new = 0, nch_new = 0;
    if (nb_rec >= 2 && nb_edge >= 1 && n_atoms > 0 && n4 > 0 &&
        ws_size > qd_b + vw_b) {
        nch_new = (n_atoms + CH_REC - 1) / CH_REC;                   // 5 for 100K
        int cap = 512;                                               // 2/CU * 256
        S_new = (cap / nch_new) & ~7;                                // 96
        size_t avail = ws_size - qd_b - vw_b;
        int S_fit = (int)(avail / ((size_t)n_atoms * sizeof(__half2))) & ~7;
        if (S_fit < S_new) S_new = S_fit;
    }

    if (S_new >= 8) {
        __half2*  qd      = (__half2*)d_ws;
        unsigned* vw      = (unsigned*)((char*)d_ws + qd_b);
        __half2*  partial = (__half2*)((char*)d_ws + qd_b + vw_b);
        int       gps     = (n4 + S_new - 1) / S_new;
        int       third   = (n4 + 2) / 3;
        int       gridA   = (third + BLK1 - 1) / BLK1;
        int       njc     = (n_atoms + AJ_CH - 1) / AJ_CH;           // 3 for 100K
        if (gridA < 1) gridA = 1;

        pc_pack_qd_h<<<(n_atoms + 255) / 256, 256, 0, stream>>>(q, dip, qd,
                                                                n_atoms);
        pc_edge_jlds<<<gridA, BLK1, lds_edge, stream>>>(
            dist, idx_j, qd, (uint4*)vw, vw, n_edges, n4, third, n_atoms, njc);
        pc_scatter_vw<CH_REC, BLK1>
            <<<S_new * nch_new, BLK1, lds_rec, stream>>>(
                idx_i, vw, partial, n_edges, n4, S_new, gps, n_atoms);
        pc_reduce_vw<<<(n_atoms + 63) / 64, 256, 0, stream>>>(
            partial, q, dip, out, n_atoms, S_new);
        return;
    }

    // ---------- OLD path (fallback, unchanged) ----------
    size_t lds_duo  = (size_t)CH_DUO  * sizeof(__half2)
                    + (size_t)(LUT_DUO  + 1) * sizeof(float2);  // 77832 B
    size_t lds_solo = (size_t)CH_SOLO * sizeof(__half2)
                    + (size_t)(LUT_SOLO + 1) * sizeof(float2);  // ~148 KB

    int nb_duo = probe_blocks((const void*)&pc_scatter_lut<CH_DUO, LUT_DUO, BLK1>,
                              BLK1, lds_duo);
    int nb_solo = probe_blocks((const void*)&pc_scatter_lut<CH_SOLO, LUT_SOLO, BLK1>,
                               BLK1, lds_solo);

    bool use_duo = (nb_duo >= 2);
    int  CH, nch, S, cap;
    size_t lds;
    if (use_duo) {
        CH  = CH_DUO;  lds = lds_duo;
        nch = (n_atoms + CH - 1) / CH;
        cap = 512;
    } else {
        CH  = CH_SOLO; lds = lds_solo;
        nch = (n_atoms + CH - 1) / CH;
        cap = 256;
    }
    S = (cap / nch) & ~7;
    if (S < 8) S = 8;

    size_t avail = (ws_size > qd_b) ? ws_size - qd_b : 0;
    int S_fit = (int)(avail / ((size_t)n_atoms * sizeof(__half2)));
    if (S_fit < S) S = S_fit & ~7;

    bool ok = (use_duo || nb_solo >= 1) && S >= 8 && n_atoms > 0;

    if (ok) {
        __half2* qd      = (__half2*)d_ws;
        __half2* partial = (__half2*)((char*)d_ws + qd_b);
        int      gps     = (n4 + S - 1) / S;

        pc_pack_qd_h<<<(n_atoms + 255) / 256, 256, 0, stream>>>(q, dip, qd,
                                                                n_atoms);
        if (use_duo)
            pc_scatter_lut<CH_DUO, LUT_DUO, BLK1>
                <<<S * nch, BLK1, lds, stream>>>(
                    dist, idx_i, idx_j, qd, partial, n_edges, n4, S, gps,
                    n_atoms, nch);
        else
            pc_scatter_lut<CH_SOLO, LUT_SOLO, BLK1>
                <<<S * nch, BLK1, lds, stream>>>(
                    dist, idx_i, idx_j, qd, partial, n_edges, n4, S, gps,
                    n_atoms, nch);
        pc_reduce_vw<<<(n_atoms + 63) / 64, 256, 0, stream>>>(
            partial, q, dip, out, n_atoms, S);
    } else {
        hipMemsetAsync(out, 0, (size_t)n_atoms * sizeof(float), stream);
        int grid = (n_edges + 255) / 256;
        pc_dipole_edges_atomic<<<grid, 256, 0, stream>>>(
            q, dip, dist, idx_i, idx_j, out, n_edges);
    }
}